// Round 10
// baseline (334.039 us; speedup 1.0000x reference)
//
#include <hip/hip_runtime.h>
#include <hip/hip_bf16.h>
#include <math.h>

// Problem constants
constexpr int N = 10000;
constexpr int E = 160000;
constexpr int B = 16;
constexpr int POOL_CHUNKS = 80;   // 80 * 125 = 10000
constexpr int MS = 72;            // m_s row stride (bf16), wave-local
constexpr int HS = 96;            // hb row stride: 4 q-sections x 24 (17 used + pad)

typedef short bf16x8 __attribute__((ext_vector_type(8)));
typedef short bf16x4 __attribute__((ext_vector_type(4)));
typedef float f32x4 __attribute__((ext_vector_type(4)));

__device__ __forceinline__ float silu_f(float x) {
    return x / (1.0f + __expf(-x));
}
__device__ __forceinline__ float bf2f(short s) {
    union { unsigned u; float f; } c; c.u = (unsigned)(unsigned short)s << 16; return c.f;
}
// async global->LDS DMA, 16B/lane. LDS dest: wave-uniform base + lane*16 (linear).
__device__ __forceinline__ void gload_lds16(const void* g, void* l) {
    __builtin_amdgcn_global_load_lds(
        (const __attribute__((address_space(1))) void*)g,
        (__attribute__((address_space(3))) void*)l, 16, 0, 0);
}

// ---------------- weight reorder bodies (q-major i-mapping) ----------------
__device__ __forceinline__ void w2_body(
        int idx, const float* __restrict__ Wsrc,
        __hip_bfloat16* __restrict__ Whi, __hip_bfloat16* __restrict__ Wlo) {
    int l = idx >> 15;
    int rem = idx & 32767;
    int kk = rem >> 11;
    int nt = (rem >> 9) & 3;
    int c  = (rem >> 5) & 15;
    int q  = (rem >> 3) & 3;
    int j  = rem & 7;
    int i = q * 16 + kk;
    int k = nt * 16 + c;
    float wv = Wsrc[(size_t)l * 32768 + i * 512 + j * 64 + k];
    __hip_bfloat16 hi = __float2bfloat16(wv);
    Whi[idx] = hi;
    Wlo[idx] = __float2bfloat16(wv - __bfloat162float(hi));
}

__device__ __forceinline__ void w2h_body(
        int idx, const float* __restrict__ Wsrc, __hip_bfloat16* __restrict__ Whi) {
    int l = idx >> 15;
    int rem = idx & 32767;
    int kk = rem >> 11;
    int nt = (rem >> 9) & 3;
    int c  = (rem >> 5) & 15;
    int q  = (rem >> 3) & 3;
    int j  = rem & 7;
    int i = q * 16 + kk;
    int k = nt * 16 + c;
    Whi[idx] = __float2bfloat16(Wsrc[(size_t)l * 32768 + i * 512 + j * 64 + k]);
}

__device__ __forceinline__ void wu1_body(
        int idx, const float* __restrict__ Wu1,
        __hip_bfloat16* __restrict__ Whi, __hip_bfloat16* __restrict__ Wlo) {
    int l = idx / 67584;
    int rem = idx % 67584;
    int kk = rem / 2048;          // 0..32
    int r2 = rem % 2048;
    int nt = (r2 >> 9) & 3;
    int c  = (r2 >> 5) & 15;
    int q  = (r2 >> 3) & 3;
    int j  = r2 & 7;
    int i = q * 33 + kk;          // 0..131
    float wv = (i < 129) ? Wu1[(size_t)l * 129 * 512 + i * 512 + j * 64 + nt * 16 + c] : 0.f;
    __hip_bfloat16 hi = __float2bfloat16(wv);
    Whi[idx] = hi;
    Wlo[idx] = __float2bfloat16(wv - __bfloat162float(hi));
}

__device__ __forceinline__ void wm1z_body(
        int idx, const float* __restrict__ Wm1, __hip_bfloat16* __restrict__ Whi) {
    int l = idx / 71680;
    int rem = idx % 71680;
    int kkn = rem >> 9;          // 0..139
    int off = rem & 511;
    int kk = kkn >> 2;
    int nt = kkn & 3;
    int c16 = off >> 5;
    int q = (off >> 3) & 3;
    int j = off & 7;
    int k = nt * 16 + c16;
    int wi = -1;
    if (kk < 17) { int i = q * 17 + kk; if (i <= 64) wi = i; }
    else if (kk < 34) { int s = q * 17 + (kk - 17); if (s <= 64) wi = 65 + s; }
    else { if (q == 0) wi = 130; }
    float wv = (wi >= 0) ? Wm1[((size_t)l * 131 + wi) * 512 + j * 64 + k] : 0.f;
    Whi[idx] = __float2bfloat16(wv);
}

// ---------------- mega pre-kernel: all weight reorders + hist zero + embed ----------------
constexpr int PB_W2H  = 0;                 // 256 blocks: Wm2 -> W2hi
constexpr int PB_WM1Z = PB_W2H  + 256;     // 560
constexpr int PB_WU1  = PB_WM1Z + 560;     // 528
constexpr int PB_WU2  = PB_WU1  + 528;     // 256
constexpr int PB_WP1  = PB_WU2  + 256;     // 128
constexpr int PB_WP2  = PB_WP1  + 128;     // 128
constexpr int PB_ZERO = PB_WP2  + 128;     // 40
constexpr int PB_EMB  = PB_ZERO + 40;      // 625
constexpr int PB_TOTAL= PB_EMB  + 625;     // 2521

__global__ __launch_bounds__(256) void k_pre(
        const float* __restrict__ Wm2, __hip_bfloat16* __restrict__ W2hi,
        const float* __restrict__ Wm1, __hip_bfloat16* __restrict__ Wm1zhi,
        const float* __restrict__ Wu1w, __hip_bfloat16* __restrict__ Wu1hi, __hip_bfloat16* __restrict__ Wu1lo,
        const float* __restrict__ Wu2w, __hip_bfloat16* __restrict__ Wu2hi, __hip_bfloat16* __restrict__ Wu2lo,
        const float* __restrict__ Wp1w, __hip_bfloat16* __restrict__ Wp1hi, __hip_bfloat16* __restrict__ Wp1lo,
        const float* __restrict__ Wp2w, __hip_bfloat16* __restrict__ Wp2hi, __hip_bfloat16* __restrict__ Wp2lo,
        int* __restrict__ hist,
        const float* __restrict__ x, const float* __restrict__ anf,
        const float* __restrict__ na, const float* __restrict__ W_emb,
        const float* __restrict__ b_emb,
        float* __restrict__ h, __hip_bfloat16* __restrict__ hb, float* __restrict__ agg) {
    __shared__ float xs[16][18];
    __shared__ float na_s[16][8];
    int tid = threadIdx.x;
    int bx = blockIdx.x;
    if (bx < PB_WM1Z) {
        w2h_body((bx - PB_W2H) * 256 + tid, Wm2, W2hi);
    } else if (bx < PB_WU1) {
        wm1z_body((bx - PB_WM1Z) * 256 + tid, Wm1, Wm1zhi);
    } else if (bx < PB_WU2) {
        wu1_body((bx - PB_WU1) * 256 + tid, Wu1w, Wu1hi, Wu1lo);
    } else if (bx < PB_WP1) {
        w2_body((bx - PB_WU2) * 256 + tid, Wu2w, Wu2hi, Wu2lo);
    } else if (bx < PB_WP2) {
        w2_body((bx - PB_WP1) * 256 + tid, Wp1w, Wp1hi, Wp1lo);
    } else if (bx < PB_ZERO) {
        w2_body((bx - PB_WP2) * 256 + tid, Wp2w, Wp2hi, Wp2lo);
    } else if (bx < PB_EMB) {
        int i = (bx - PB_ZERO) * 256 + tid;
        if (i < N) hist[i] = 0;
    } else {
        // ---- embed: h fp32 + hb (q-sectioned) + agg zero ----
        int eb = bx - PB_EMB;
        int w = tid >> 6, l = tid & 63;
        int n0 = eb * 16;
        {
            int r = tid >> 4, c = tid & 15;
            xs[r][c] = x[(size_t)(n0 + r) * 16 + c];
        }
        if (tid < 16) xs[tid][16] = anf[n0 + tid];
        if (tid < 128) na_s[tid >> 3][tid & 7] = na[(size_t)n0 * 8 + tid];
        float4 z4 = {0.f, 0.f, 0.f, 0.f};
        ((float4*)(agg + (size_t)eb * 1024))[tid] = z4;
        for (int t = tid; t < 192; t += 256)
            ((float4*)(hb + (size_t)n0 * HS))[t] = z4;
        __syncthreads();
        float acc[4];
#pragma unroll
        for (int t = 0; t < 4; ++t) acc[t] = b_emb[l];
        for (int i = 0; i < 17; ++i) {
#pragma unroll
            for (int j = 0; j < 8; ++j) {
                float wv = W_emb[(i * 8 + j) * 64 + l];
#pragma unroll
                for (int t = 0; t < 4; ++t) {
                    int nn = w * 4 + t;
                    acc[t] = fmaf(xs[nn][i] * na_s[nn][j], wv, acc[t]);
                }
            }
        }
        int slot = (l / 17) * 24 + l % 17;
#pragma unroll
        for (int t = 0; t < 4; ++t) {
            int n = n0 + w * 4 + t;
            h[(size_t)n * 64 + l] = acc[t];
            hb[(size_t)n * HS + slot] = __float2bfloat16(acc[t]);
        }
        if (tid < 16) hb[(size_t)(n0 + tid) * HS + 85] = __float2bfloat16(xs[tid][16]);
    }
}

// ---------------- edge sort by dst: histogram / scan / scatter+materialize ----------------
__global__ __launch_bounds__(256) void k_hist(
        const int* __restrict__ eidx, int* __restrict__ hist) {
    int e = blockIdx.x * 256 + threadIdx.x;
    if (e < E) atomicAdd(&hist[eidx[E + e]], 1);
}

// single-block exclusive scan over N=10000 bins -> cursor
__global__ __launch_bounds__(1024) void k_scan(
        const int* __restrict__ hist, int* __restrict__ cursor) {
    __shared__ int wsum[16];
    int t = threadIdx.x;
    int base = t * 10;
    int loc[10];
    int s = 0;
#pragma unroll
    for (int i = 0; i < 10; ++i) {
        int v = (base + i < N) ? hist[base + i] : 0;
        loc[i] = s;
        s += v;
    }
    int lane = t & 63, w = t >> 6;
    int incl = s;
    for (int off = 1; off < 64; off <<= 1) {
        int u = __shfl_up(incl, off, 64);
        if (lane >= off) incl += u;
    }
    if (lane == 63) wsum[w] = incl;
    __syncthreads();
    if (t == 0) {
        int a = 0;
        for (int i2 = 0; i2 < 16; ++i2) { int v = wsum[i2]; wsum[i2] = a; a += v; }
    }
    __syncthreads();
    int excl = incl - s + wsum[w];
#pragma unroll
    for (int i = 0; i < 10; ++i) {
        int p = base + i;
        if (p < N) cursor[p] = excl + loc[i];
    }
}

// scatter into dst-sorted records (coalesced reads; 48B record = 1-2 line touches/edge)
__global__ __launch_bounds__(256) void k_scatter_sort(
        const int* __restrict__ eidx, const float* __restrict__ ea,
        const float* __restrict__ amf, int* __restrict__ cursor,
        int* __restrict__ dstS, float4* __restrict__ recs) {
    int e = blockIdx.x * 256 + threadIdx.x;
    if (e < E) {
        int d = eidx[E + e];
        int p = atomicAdd(&cursor[d], 1);
        dstS[p] = d;
        float4 a0 = ((const float4*)ea)[(size_t)e * 2];
        float4 a1 = ((const float4*)ea)[(size_t)e * 2 + 1];
        float4 r0 = {__int_as_float(eidx[e]), amf[e], a0.x, a0.y};
        float4 r1 = {a0.z, a0.w, a1.x, a1.y};
        float4 r2 = {a1.z, a1.w, 0.f, 0.f};
        recs[(size_t)p * 3 + 0] = r0;
        recs[(size_t)p * 3 + 1] = r1;
        recs[(size_t)p * 3 + 2] = r2;
    }
}

// ---------------- K3: edge kernel — LDS-staged weights via async DMA (r9, proven) ----------------
__global__ __launch_bounds__(256, 3) void k_edge(
        const float4* __restrict__ recs, const int* __restrict__ dstS,
        const __hip_bfloat16* __restrict__ hb,
        const __hip_bfloat16* __restrict__ W1hi, const float* __restrict__ bm1_l,
        const __hip_bfloat16* __restrict__ W2hi,
        const float* __restrict__ bm2_l, float* __restrict__ agg) {
    __shared__ __align__(16) __hip_bfloat16 wbuf[2][8192];   // 2 x 16KB weight chunks
    // per-wave private 4608B region: m_s [32][72] bf16; m2 chunk [16][66] f32 overlaid
    __shared__ __align__(16) char smem_u[4 * 4608];          // 18432 B
    __shared__ int dst_s[128];
    int tid = threadIdx.x;
    int l = tid & 63, w = tid >> 6;
    int e0 = blockIdx.x * 128;
    __hip_bfloat16* m_s = (__hip_bfloat16*)(smem_u + w * 4608);
    float* m2 = (float*)(smem_u + w * 4608);

    if (l < 32) dst_s[w * 32 + l] = dstS[e0 + w * 32 + l];

    int c16 = l & 15, q = l >> 4;
    int e0w = w * 32;
    float eaA[2][8], amfA[2];
    int dL[2], sL[2];
#pragma unroll
    for (int mt = 0; mt < 2; ++mt) {
        int e = e0 + e0w + mt * 16 + c16;
        float4 r0 = recs[(size_t)e * 3];
        float4 r1 = recs[(size_t)e * 3 + 1];
        float4 r2 = recs[(size_t)e * 3 + 2];
        sL[mt] = __float_as_int(r0.x);
        amfA[mt] = r0.y;
        eaA[mt][0] = r0.z; eaA[mt][1] = r0.w;
        eaA[mt][2] = r1.x; eaA[mt][3] = r1.y; eaA[mt][4] = r1.z; eaA[mt][5] = r1.w;
        eaA[mt][6] = r2.x; eaA[mt][7] = r2.y;
        dL[mt] = dstS[e];
    }
    float bR1[4], bR2[4];
#pragma unroll
    for (int nt = 0; nt < 4; ++nt) {
        bR1[nt] = bm1_l[nt * 16 + c16];
        bR2[nt] = bm2_l[nt * 16 + c16];
    }
    int lofs = (c16 * 4 + q) * 8;
    f32x4 zero4 = {0.f, 0.f, 0.f, 0.f};

    // async-DMA staging of one 16KB chunk (nk*4KB): per round r, wave w covers 1KB.
    auto stage = [&](const __hip_bfloat16* src, __hip_bfloat16* dbuf, int nk) {
        const char* g = (const char*)src;
        char* lb = (char*)dbuf;
#pragma unroll
        for (int r = 0; r < 4; ++r)
            if (r < nk)
                gload_lds16(g + (size_t)(r * 256 + w * 64 + l) * 16,
                            lb + (r * 256 + w * 64) * 16);
    };

    // gather D-side fragments only (S-side deferred to c==3)
    bf16x4 xD[2][5];
#pragma unroll
    for (int mt = 0; mt < 2; ++mt) {
        const __hip_bfloat16* bd = hb + (size_t)dL[mt] * HS + q * 24;
#pragma unroll
        for (int t = 0; t < 5; ++t)
            xD[mt][t] = *(const bf16x4*)(bd + t * 4);
    }

    // issue chunk 0 DMA (drained by the first in-loop barrier)
    stage(W1hi, wbuf[0], 4);

    f32x4 acc[2][4];
#pragma unroll
    for (int mt = 0; mt < 2; ++mt)
#pragma unroll
        for (int nt = 0; nt < 4; ++nt) acc[mt][nt] = zero4;
    bf16x4 xS[2][5];    // loaded at c==3
    bf16x4 mR[2][4];    // loaded at c==8

    // 13 chunks: c 0..8 = W1 (8x4kk + 1x3kk), c 9..12 = W2 (4x4kk)
#pragma unroll
    for (int c = 0; c < 13; ++c) {
        __syncthreads();   // drains each wave's own DMA (vmcnt(0)) then syncs -> buf[c&1] ready
        if (c + 1 < 13) {
            const __hip_bfloat16* nsrc = (c + 1 < 9) ? (W1hi + (c + 1) * 8192)
                                                     : (W2hi + (c + 1 - 9) * 8192);
            stage(nsrc, wbuf[(c + 1) & 1], (c + 1 == 8) ? 3 : 4);
        }
        if (c == 3) {
#pragma unroll
            for (int mt = 0; mt < 2; ++mt) {
                const __hip_bfloat16* bs = hb + (size_t)sL[mt] * HS + q * 24;
#pragma unroll
                for (int t = 0; t < 5; ++t)
                    xS[mt][t] = *(const bf16x4*)(bs + t * 4);
            }
        }
        const __hip_bfloat16* wb = wbuf[c & 1];
        if (c < 9) {
            const int nkk = (c == 8) ? 3 : 4;
#pragma unroll
            for (int kkl = 0; kkl < 4; ++kkl) {
                if (kkl < nkk) {
                    const int u = c * 4 + kkl;      // 0..34
                    bf16x8 bh[4];
#pragma unroll
                    for (int nt = 0; nt < 4; ++nt)
                        bh[nt] = *(const bf16x8*)&wb[(kkl * 4 + nt) * 512 + lofs];
#pragma unroll
                    for (int mt = 0; mt < 2; ++mt) {
                        float xv;
                        if (u < 17)      xv = bf2f(xD[mt][u >> 2][u & 3]);
                        else if (u < 34) { const int s = u - 17; xv = bf2f(xS[mt][s >> 2][s & 3]); }
                        else             xv = (q == 0) ? amfA[mt] : 0.f;
                        union { bf16x8 v; __hip_bfloat16 hx[8]; } au;
#pragma unroll
                        for (int j = 0; j < 8; ++j) au.hx[j] = __float2bfloat16(xv * eaA[mt][j]);
#pragma unroll
                        for (int nt = 0; nt < 4; ++nt)
                            acc[mt][nt] = __builtin_amdgcn_mfma_f32_16x16x32_bf16(au.v, bh[nt], acc[mt][nt], 0, 0, 0);
                    }
                }
            }
        } else {
#pragma unroll
            for (int kkl = 0; kkl < 4; ++kkl) {
                const int kk = (c - 9) * 4 + kkl;   // 0..15
                bf16x8 bh[4];
#pragma unroll
                for (int nt = 0; nt < 4; ++nt)
                    bh[nt] = *(const bf16x8*)&wb[(kkl * 4 + nt) * 512 + lofs];
#pragma unroll
                for (int mt = 0; mt < 2; ++mt) {
                    float mv = bf2f(mR[mt][kk >> 2][kk & 3]);
                    union { bf16x8 v; __hip_bfloat16 hx[8]; } au;
#pragma unroll
                    for (int j = 0; j < 8; ++j) au.hx[j] = __float2bfloat16(mv * eaA[mt][j]);
#pragma unroll
                    for (int nt = 0; nt < 4; ++nt)
                        acc[mt][nt] = __builtin_amdgcn_mfma_f32_16x16x32_bf16(au.v, bh[nt], acc[mt][nt], 0, 0, 0);
                }
            }
        }
        if (c == 8) {
#pragma unroll
            for (int mt = 0; mt < 2; ++mt)
#pragma unroll
                for (int nt = 0; nt < 4; ++nt) {
                    int kd = nt * 16 + c16;
                    float bias = bR1[nt];
#pragma unroll
                    for (int r = 0; r < 4; ++r) {
                        int el = mt * 16 + q * 4 + r;
                        m_s[el * MS + kd] = __float2bfloat16(silu_f(bias + acc[mt][nt][r]));
                    }
                }
#pragma unroll
            for (int mt = 0; mt < 2; ++mt)
#pragma unroll
                for (int t = 0; t < 4; ++t)
                    mR[mt][t] = *(const bf16x4*)&m_s[(mt * 16 + c16) * MS + q * 16 + t * 4];
            asm volatile("" ::: "memory");
#pragma unroll
            for (int mt = 0; mt < 2; ++mt)
#pragma unroll
                for (int nt = 0; nt < 4; ++nt) acc[mt][nt] = zero4;   // reuse for phase 2
        }
    }

    // chunked epilogue: per mt-chunk write 16 rows of m2 (own region), run-length reduce, atomics.
#pragma unroll
    for (int mt = 0; mt < 2; ++mt) {
#pragma unroll
        for (int nt = 0; nt < 4; ++nt) {
            int kd = nt * 16 + c16;
            float bias = bR2[nt];
#pragma unroll
            for (int r = 0; r < 4; ++r)
                m2[(q * 4 + r) * 66 + kd] = silu_f(bias + acc[mt][nt][r]);
        }
        int rb = w * 32 + mt * 16;
        float run = 0.f;
        int cur_d = dst_s[rb];
        for (int i = 0; i < 16; ++i) {
            int d = dst_s[rb + i];                 // wave-uniform
            if (d != cur_d) {
                atomicAdd(&agg[(size_t)cur_d * 64 + l], run);
                run = 0.f;
                cur_d = d;
            }
            run += m2[i * 66 + l];
        }
        atomicAdd(&agg[(size_t)cur_d * 64 + l], run);
        asm volatile("" ::: "memory");
    }
}

// ---------------- K4: node update — nt-split waves + async-DMA weight staging ----------------
// r9 template ported: each wave owns output cols w*16..w*16+15 for ALL K (no part_s, no
// reduction); all 4 waves consume the same staged chunk (2kk: 8KB hi + 8KB lo) from a 32KB
// LDS dbuf filled by global_load_lds (zero staging VGPRs), one barrier/chunk, DMA 1 ahead.
// Chunks: 0..16 = Wu1 (33kk, chunk16=1kk), 17..24 = Wu2. acc = one f32x4 (no spill class).
__global__ __launch_bounds__(256) void k_upd_hb(
        const float* __restrict__ h_in, const float* __restrict__ anf,
        const float* __restrict__ na, const float* __restrict__ agg_in,
        const __hip_bfloat16* __restrict__ W1hi, const __hip_bfloat16* __restrict__ W1lo,
        const float* __restrict__ bu1_l,
        const __hip_bfloat16* __restrict__ W2hi_, const __hip_bfloat16* __restrict__ W2lo_,
        const float* __restrict__ bu2_l,
        float* __restrict__ h, __hip_bfloat16* __restrict__ hb, float* __restrict__ agg) {
    __shared__ __align__(16) __hip_bfloat16 wbuf[2][8192];   // [0..4096) hi, [4096..8192) lo
    __shared__ __align__(16) __hip_bfloat16 xa_s[16 * 136];
    __shared__ __align__(16) __hip_bfloat16 u1_s[16 * 72];
    int tid = threadIdx.x;
    int w = tid >> 6, l = tid & 63;
    int n0 = blockIdx.x * 16;
    for (int idx = tid; idx < 16 * 132; idx += 256) {
        int r = idx / 132, c = idx % 132;
        int n = n0 + r;
        float v;
        if (c < 64) v = h_in[(size_t)n * 64 + c];
        else if (c == 64) v = anf[n];
        else if (c < 129) v = agg_in[(size_t)n * 64 + (c - 65)];
        else v = 0.f;
        xa_s[r * 136 + c] = __float2bfloat16(v);
    }
    int c16 = l & 15, q = l >> 4;
    float naA[8];
#pragma unroll
    for (int j = 0; j < 8; ++j) naA[j] = na[(size_t)(n0 + c16) * 8 + j];
    int col = w * 16 + c16;
    float bu1R = bu1_l[col], bu2R = bu2_l[col];
    float4 z4 = {0.f, 0.f, 0.f, 0.f};
    ((float4*)(agg + (size_t)blockIdx.x * 1024))[tid] = z4;
    for (int t = tid; t < 192; t += 256)
        ((float4*)(hb + (size_t)n0 * HS))[t] = z4;
    int lofs = (c16 * 4 + q) * 8;

    // DMA one hi/lo chunk: nr rounds each of 4KB (256 lanes x 16B)
    auto stage_ul = [&](const __hip_bfloat16* hi, const __hip_bfloat16* lo,
                        __hip_bfloat16* buf, int nr) {
        const char* gh = (const char*)hi;
        const char* gl = (const char*)lo;
        char* bh = (char*)buf;
        char* bl = (char*)(buf + 4096);
#pragma unroll
        for (int r = 0; r < 2; ++r)
            if (r < nr) {
                gload_lds16(gh + (size_t)(r * 256 + w * 64 + l) * 16, bh + (r * 256 + w * 64) * 16);
                gload_lds16(gl + (size_t)(r * 256 + w * 64 + l) * 16, bl + (r * 256 + w * 64) * 16);
            }
    };

    stage_ul(W1hi, W1lo, wbuf[0], 2);
    f32x4 zero4 = {0.f, 0.f, 0.f, 0.f};
    f32x4 acc = zero4;
#pragma unroll 1
    for (int c = 0; c < 25; ++c) {
        __syncthreads();            // drains own DMA + publishes buf[c&1] + orders u1_s
        if (c + 1 < 25) {
            int cn = c + 1;
            const __hip_bfloat16 *nh, *nl;
            int nr = 2;
            if (cn < 17) { nh = W1hi + cn * 4096; nl = W1lo + cn * 4096; if (cn == 16) nr = 1; }
            else         { nh = W2hi_ + (cn - 17) * 4096; nl = W2lo_ + (cn - 17) * 4096; }
            stage_ul(nh, nl, wbuf[cn & 1], nr);
        }
        const __hip_bfloat16* wb = wbuf[c & 1];
        const __hip_bfloat16* xs;
        int xstr, Lq, kk0, nkl = 2;
        if (c < 17) { xs = xa_s; xstr = 136; Lq = 33; kk0 = c * 2; if (c == 16) nkl = 1; }
        else        { xs = u1_s; xstr = 72;  Lq = 16; kk0 = (c - 17) * 2; }
#pragma unroll
        for (int kl = 0; kl < 2; ++kl)
            if (kl < nkl) {
                float mv = __bfloat162float(xs[c16 * xstr + q * Lq + kk0 + kl]);
                union { bf16x8 v; __hip_bfloat16 hx[8]; } au;
#pragma unroll
                for (int j = 0; j < 8; ++j) au.hx[j] = __float2bfloat16(mv * naA[j]);
                bf16x8 bh = *(const bf16x8*)&wb[(kl * 4 + w) * 512 + lofs];
                bf16x8 bl = *(const bf16x8*)&wb[4096 + (kl * 4 + w) * 512 + lofs];
                acc = __builtin_amdgcn_mfma_f32_16x16x32_bf16(au.v, bh, acc, 0, 0, 0);
                acc = __builtin_amdgcn_mfma_f32_16x16x32_bf16(au.v, bl, acc, 0, 0, 0);
            }
        if (c == 16) {
            // stage1 epilogue -> u1_s (published by the c==17 barrier)
#pragma unroll
            for (int r = 0; r < 4; ++r)
                u1_s[(q * 4 + r) * 72 + col] = __float2bfloat16(silu_f(acc[r] + bu1R));
            acc = zero4;
        }
    }
    int slot = (col / 17) * 24 + col % 17;
#pragma unroll
    for (int r = 0; r < 4; ++r) {
        int n = n0 + q * 4 + r;
        float hn = h[(size_t)n * 64 + col] + acc[r] + bu2R;
        h[(size_t)n * 64 + col] = hn;
        hb[(size_t)n * HS + slot] = __float2bfloat16(hn);
    }
    if (tid < 16) hb[(size_t)(n0 + tid) * HS + 85] = __float2bfloat16(anf[n0 + tid]);
}

// ---------------- K6: fused node update (layer 1) + prepool — same template, 41 chunks ----------------
// Chunks: 0..16 Wu1(xa), 17..24 Wu2(u1), 25..32 Wp1(x2), 33..40 Wp2(u1).
__global__ __launch_bounds__(256) void k_upd_prepool(
        const float* __restrict__ h_in, const float* __restrict__ anf,
        const float* __restrict__ na, const float* __restrict__ agg_in,
        const __hip_bfloat16* __restrict__ W1hi, const __hip_bfloat16* __restrict__ W1lo,
        const float* __restrict__ bu1_l,
        const __hip_bfloat16* __restrict__ W2hi_, const __hip_bfloat16* __restrict__ W2lo_,
        const float* __restrict__ bu2_l,
        const __hip_bfloat16* __restrict__ Wp1hi, const __hip_bfloat16* __restrict__ Wp1lo,
        const float* __restrict__ bp1,
        const __hip_bfloat16* __restrict__ Wp2hi, const __hip_bfloat16* __restrict__ Wp2lo,
        const float* __restrict__ bp2,
        float* __restrict__ p2) {
    __shared__ __align__(16) __hip_bfloat16 wbuf[2][8192];
    __shared__ __align__(16) __hip_bfloat16 xa_s[16 * 136];
    __shared__ __align__(16) __hip_bfloat16 u1_s[16 * 72];
    __shared__ __align__(16) __hip_bfloat16 x2_s[16 * 72];
    int tid = threadIdx.x;
    int w = tid >> 6, l = tid & 63;
    int n0 = blockIdx.x * 16;
    for (int idx = tid; idx < 16 * 132; idx += 256) {
        int r = idx / 132, c = idx % 132;
        int n = n0 + r;
        float v;
        if (c < 64) v = h_in[(size_t)n * 64 + c];
        else if (c == 64) v = anf[n];
        else if (c < 129) v = agg_in[(size_t)n * 64 + (c - 65)];
        else v = 0.f;
        xa_s[r * 136 + c] = __float2bfloat16(v);
    }
    int c16 = l & 15, q = l >> 4;
    float naA[8];
#pragma unroll
    for (int j = 0; j < 8; ++j) naA[j] = na[(size_t)(n0 + c16) * 8 + j];
    int col = w * 16 + c16;
    float bu1R = bu1_l[col], bu2R = bu2_l[col];
    float bp1R = bp1[col], bp2R = bp2[col];
    int lofs = (c16 * 4 + q) * 8;

    auto stage_ul = [&](const __hip_bfloat16* hi, const __hip_bfloat16* lo,
                        __hip_bfloat16* buf, int nr) {
        const char* gh = (const char*)hi;
        const char* gl = (const char*)lo;
        char* bh = (char*)buf;
        char* bl = (char*)(buf + 4096);
#pragma unroll
        for (int r = 0; r < 2; ++r)
            if (r < nr) {
                gload_lds16(gh + (size_t)(r * 256 + w * 64 + l) * 16, bh + (r * 256 + w * 64) * 16);
                gload_lds16(gl + (size_t)(r * 256 + w * 64 + l) * 16, bl + (r * 256 + w * 64) * 16);
            }
    };

    stage_ul(W1hi, W1lo, wbuf[0], 2);
    f32x4 zero4 = {0.f, 0.f, 0.f, 0.f};
    f32x4 acc = zero4;
#pragma unroll 1
    for (int c = 0; c < 41; ++c) {
        __syncthreads();
        if (c + 1 < 41) {
            int cn = c + 1;
            const __hip_bfloat16 *nh, *nl;
            int nr = 2;
            if (cn < 17)      { nh = W1hi + cn * 4096;        nl = W1lo + cn * 4096;        if (cn == 16) nr = 1; }
            else if (cn < 25) { nh = W2hi_ + (cn - 17) * 4096; nl = W2lo_ + (cn - 17) * 4096; }
            else if (cn < 33) { nh = Wp1hi + (cn - 25) * 4096; nl = Wp1lo + (cn - 25) * 4096; }
            else              { nh = Wp2hi + (cn - 33) * 4096; nl = Wp2lo + (cn - 33) * 4096; }
            stage_ul(nh, nl, wbuf[cn & 1], nr);
        }
        const __hip_bfloat16* wb = wbuf[c & 1];
        const __hip_bfloat16* xs;
        int xstr, Lq, kk0, nkl = 2;
        if (c < 17)      { xs = xa_s; xstr = 136; Lq = 33; kk0 = c * 2; if (c == 16) nkl = 1; }
        else if (c < 25) { xs = u1_s; xstr = 72;  Lq = 16; kk0 = (c - 17) * 2; }
        else if (c < 33) { xs = x2_s; xstr = 72;  Lq = 16; kk0 = (c - 25) * 2; }
        else             { xs = u1_s; xstr = 72;  Lq = 16; kk0 = (c - 33) * 2; }
#pragma unroll
        for (int kl = 0; kl < 2; ++kl)
            if (kl < nkl) {
                float mv = __bfloat162float(xs[c16 * xstr + q * Lq + kk0 + kl]);
                union { bf16x8 v; __hip_bfloat16 hx[8]; } au;
#pragma unroll
                for (int j = 0; j < 8; ++j) au.hx[j] = __float2bfloat16(mv * naA[j]);
                bf16x8 bh = *(const bf16x8*)&wb[(kl * 4 + w) * 512 + lofs];
                bf16x8 bl = *(const bf16x8*)&wb[4096 + (kl * 4 + w) * 512 + lofs];
                acc = __builtin_amdgcn_mfma_f32_16x16x32_bf16(au.v, bh, acc, 0, 0, 0);
                acc = __builtin_amdgcn_mfma_f32_16x16x32_bf16(au.v, bl, acc, 0, 0, 0);
            }
        if (c == 16) {
#pragma unroll
            for (int r = 0; r < 4; ++r)
                u1_s[(q * 4 + r) * 72 + col] = __float2bfloat16(silu_f(acc[r] + bu1R));
            acc = zero4;
        } else if (c == 24) {
#pragma unroll
            for (int r = 0; r < 4; ++r) {
                int n = n0 + q * 4 + r;
                float hn = h_in[(size_t)n * 64 + col] + acc[r] + bu2R;
                x2_s[(q * 4 + r) * 72 + col] = __float2bfloat16(hn);
            }
            acc = zero4;
        } else if (c == 32) {
#pragma unroll
            for (int r = 0; r < 4; ++r)
                u1_s[(q * 4 + r) * 72 + col] = __float2bfloat16(silu_f(acc[r] + bp1R));
            acc = zero4;
        }
    }
#pragma unroll
    for (int r = 0; r < 4; ++r)
        p2[(size_t)(n0 + q * 4 + r) * 64 + col] = acc[r] + bp2R;
}

// ---------------- K_pool ----------------
__global__ __launch_bounds__(256) void k_pool(
        const float* __restrict__ p2, const int* __restrict__ batch,
        float* __restrict__ partial_p, float* __restrict__ partial_cnt) {
    __shared__ float acc_s[16 * 64];
    __shared__ float cnt_s[16];
    int tid = threadIdx.x;
    for (int idx = tid; idx < 1024; idx += 256) acc_s[idx] = 0.f;
    if (tid < 16) cnt_s[tid] = 0.f;
    __syncthreads();
    int w = tid >> 6, k = tid & 63;
    int base = blockIdx.x * 125;
    for (int i = 0; i < 32; ++i) {
        int nl = i * 4 + w;
        if (nl < 125) {
            int n = base + nl;
            int b = batch[n];
            atomicAdd(&acc_s[b * 64 + k], p2[(size_t)n * 64 + k]);
            if (k == 0) atomicAdd(&cnt_s[b], 1.0f);
        }
    }
    __syncthreads();
    for (int idx = tid; idx < 1024; idx += 256)
        partial_p[(size_t)blockIdx.x * 1024 + idx] = acc_s[idx];
    if (tid < 16) partial_cnt[blockIdx.x * 16 + tid] = cnt_s[tid];
}

// ---------------- K7: reduce partials, mean, final MLP ----------------
__global__ __launch_bounds__(1024) void k_final(
        const float* __restrict__ partial_p, const float* __restrict__ partial_cnt,
        const float* __restrict__ Wq1, const float* __restrict__ bq1,
        const float* __restrict__ Wq2, const float* __restrict__ bq2,
        float* __restrict__ out) {
    __shared__ float g[16][64];
    int b = threadIdx.x >> 6, k = threadIdx.x & 63;
    float s = 0.f, cc = 0.f;
    for (int c = 0; c < POOL_CHUNKS; ++c) s += partial_p[(size_t)c * 1024 + b * 64 + k];
    for (int c = 0; c < POOL_CHUNKS; ++c) cc += partial_cnt[c * 16 + b];
    g[b][k] = s / fmaxf(cc, 1.0f);
    __syncthreads();
    float acc = bq1[k];
#pragma unroll
    for (int i = 0; i < 64; ++i) acc = fmaf(g[b][i], Wq1[i * 64 + k], acc);
    float v = silu_f(acc) * Wq2[k];
#pragma unroll
    for (int off = 32; off > 0; off >>= 1) v += __shfl_down(v, off, 64);
    if (k == 0) out[b] = v + bq2[0];
}

extern "C" void kernel_launch(void* const* d_in, const int* in_sizes, int n_in,
                              void* d_out, int out_size, void* d_ws, size_t ws_size,
                              hipStream_t stream) {
    const float* x    = (const float*)d_in[0];
    const int*   eidx = (const int*)  d_in[1];
    const float* ea   = (const float*)d_in[2];
    const float* na   = (const float*)d_in[3];
    const float* amf  = (const float*)d_in[4];
    const float* anf  = (const float*)d_in[5];
    const int*   batch= (const int*)  d_in[6];
    const float* W_emb= (const float*)d_in[7];
    const float* b_emb= (const float*)d_in[8];
    const float* Wm1  = (const float*)d_in[9];
    const float* bm1  = (const float*)d_in[10];
    const float* Wm2  = (const float*)d_in[11];
    const float* bm2  = (const float*)d_in[12];
    const float* Wu1  = (const float*)d_in[13];
    const float* bu1  = (const float*)d_in[14];
    const float* Wu2  = (const float*)d_in[15];
    const float* bu2  = (const float*)d_in[16];
    const float* Wp1  = (const float*)d_in[17];
    const float* bp1  = (const float*)d_in[18];
    const float* Wp2  = (const float*)d_in[19];
    const float* bp2  = (const float*)d_in[20];
    const float* Wq1  = (const float*)d_in[21];
    const float* bq1  = (const float*)d_in[22];
    const float* Wq2  = (const float*)d_in[23];
    const float* bq2  = (const float*)d_in[24];

    float* ws = (float*)d_ws;
    float* h      = ws;                            // N*64
    float* agg    = h + (size_t)N * 64;            // N*64
    float* p2     = agg + (size_t)N * 64;          // N*64
    float* part_p = p2 + (size_t)N * 64;           // 80*1024
    float* part_c = part_p + POOL_CHUNKS * 1024;   // 80*16
    float* fend   = part_c + POOL_CHUNKS * 16;
    __hip_bfloat16* hb     = (__hip_bfloat16*)fend;          // N*96
    __hip_bfloat16* W2hi   = hb + (size_t)N * HS;            // 2*32768
    __hip_bfloat16* Wm1zhi = W2hi + 65536;                   // 2*71680
    __hip_bfloat16* Wu1hi  = Wm1zhi + 143360;                // 2*67584
    __hip_bfloat16* Wu1lo  = Wu1hi + 135168;
    __hip_bfloat16* Wu2hi  = Wu1lo + 135168;                 // 2*32768
    __hip_bfloat16* Wu2lo  = Wu2hi + 65536;
    __hip_bfloat16* Wp1hi  = Wu2lo + 65536;                  // 32768
    __hip_bfloat16* Wp1lo  = Wp1hi + 32768;
    __hip_bfloat16* Wp2hi  = Wp1lo + 32768;
    __hip_bfloat16* Wp2lo  = Wp2hi + 32768;
    int* hist   = (int*)(Wp2lo + 32768);                     // N
    int* cursor = hist + N;                                  // N
    int* dstS   = cursor + N;                                // E
    float4* recs = (float4*)(dstS + E);                      // E * 3 float4 (48B/edge)

    // mega pre-kernel: all weight reorders + hist zero + embed(+agg/hb init)
    k_pre<<<PB_TOTAL, 256, 0, stream>>>(
        Wm2, W2hi, Wm1, Wm1zhi, Wu1, Wu1hi, Wu1lo, Wu2, Wu2hi, Wu2lo,
        Wp1, Wp1hi, Wp1lo, Wp2, Wp2hi, Wp2lo, hist,
        x, anf, na, W_emb, b_emb, h, hb, agg);

    // dst-sort + materialize sorted edge records (reused by both edge dispatches)
    k_hist<<<(E + 255) / 256, 256, 0, stream>>>(eidx, hist);
    k_scan<<<1, 1024, 0, stream>>>(hist, cursor);
    k_scatter_sort<<<(E + 255) / 256, 256, 0, stream>>>(eidx, ea, amf, cursor, dstS, recs);

    k_edge<<<E / 128, 256, 0, stream>>>(recs, dstS, hb,
                                        Wm1zhi, bm1, W2hi, bm2, agg);
    k_upd_hb<<<625, 256, 0, stream>>>(h, anf, na, agg,
                                      Wu1hi, Wu1lo, bu1,
                                      Wu2hi, Wu2lo, bu2,
                                      h, hb, agg);
    k_edge<<<E / 128, 256, 0, stream>>>(recs, dstS, hb,
                                        Wm1zhi + 71680, bm1 + 64,
                                        W2hi + 32768, bm2 + 64, agg);
    k_upd_prepool<<<625, 256, 0, stream>>>(h, anf, na, agg,
                                           Wu1hi + 67584, Wu1lo + 67584, bu1 + 64,
                                           Wu2hi + 32768, Wu2lo + 32768, bu2 + 64,
                                           Wp1hi, Wp1lo, bp1, Wp2hi, Wp2lo, bp2, p2);
    k_pool<<<POOL_CHUNKS, 256, 0, stream>>>(p2, batch, part_p, part_c);
    k_final<<<1, 1024, 0, stream>>>(part_p, part_c, Wq1, bq1, Wq2, bq2, (float*)d_out);
}

// Round 12
// 328.170 us; speedup vs baseline: 1.0179x; 1.0179x over previous
//
#include <hip/hip_runtime.h>
#include <hip/hip_bf16.h>
#include <math.h>

// Problem constants
constexpr int N = 10000;
constexpr int E = 160000;
constexpr int B = 16;
constexpr int POOL_CHUNKS = 80;   // 80 * 125 = 10000
constexpr int MS = 72;            // m_s row stride (bf16), wave-local
constexpr int HS = 96;            // hb row stride: 4 q-sections x 24 (17 used + pad)

typedef short bf16x8 __attribute__((ext_vector_type(8)));
typedef short bf16x4 __attribute__((ext_vector_type(4)));
typedef float f32x4 __attribute__((ext_vector_type(4)));

__device__ __forceinline__ float silu_f(float x) {
    return x / (1.0f + __expf(-x));
}
__device__ __forceinline__ float bf2f(short s) {
    union { unsigned u; float f; } c; c.u = (unsigned)(unsigned short)s << 16; return c.f;
}
// async global->LDS DMA, 16B/lane. LDS dest: wave-uniform base + lane*16 (linear).
__device__ __forceinline__ void gload_lds16(const void* g, void* l) {
    __builtin_amdgcn_global_load_lds(
        (const __attribute__((address_space(1))) void*)g,
        (__attribute__((address_space(3))) void*)l, 16, 0, 0);
}

// ---------------- weight reorder bodies ----------------
// Slot layout within each 512-elem row: (q*16+c16)*8+j  (was (c16*4+q)*8+j).
// Value-identical remap: lane l = q*16+c16 reads lofs = l*8 -> the wave's
// ds_read_b128 covers 1024 contiguous bytes = zero bank conflicts (r10: 4.48M).
// r11 lesson: this change is provably bit-identical per lane; the r11 failure
// came from the simultaneous 512-thread k_edge restructure (reverted).
__device__ __forceinline__ void w2_body(
        int idx, const float* __restrict__ Wsrc,
        __hip_bfloat16* __restrict__ Whi, __hip_bfloat16* __restrict__ Wlo) {
    int l = idx >> 15;
    int rem = idx & 32767;
    int kk = rem >> 11;
    int nt = (rem >> 9) & 3;
    int q  = (rem >> 7) & 3;
    int c  = (rem >> 3) & 15;
    int j  = rem & 7;
    int i = q * 16 + kk;
    int k = nt * 16 + c;
    float wv = Wsrc[(size_t)l * 32768 + i * 512 + j * 64 + k];
    __hip_bfloat16 hi = __float2bfloat16(wv);
    Whi[idx] = hi;
    Wlo[idx] = __float2bfloat16(wv - __bfloat162float(hi));
}

__device__ __forceinline__ void w2h_body(
        int idx, const float* __restrict__ Wsrc, __hip_bfloat16* __restrict__ Whi) {
    int l = idx >> 15;
    int rem = idx & 32767;
    int kk = rem >> 11;
    int nt = (rem >> 9) & 3;
    int q  = (rem >> 7) & 3;
    int c  = (rem >> 3) & 15;
    int j  = rem & 7;
    int i = q * 16 + kk;
    int k = nt * 16 + c;
    Whi[idx] = __float2bfloat16(Wsrc[(size_t)l * 32768 + i * 512 + j * 64 + k]);
}

__device__ __forceinline__ void wu1_body(
        int idx, const float* __restrict__ Wu1,
        __hip_bfloat16* __restrict__ Whi, __hip_bfloat16* __restrict__ Wlo) {
    int l = idx / 67584;
    int rem = idx % 67584;
    int kk = rem / 2048;          // 0..32
    int r2 = rem % 2048;
    int nt = (r2 >> 9) & 3;
    int q  = (r2 >> 7) & 3;
    int c  = (r2 >> 3) & 15;
    int j  = r2 & 7;
    int i = q * 33 + kk;          // 0..131
    float wv = (i < 129) ? Wu1[(size_t)l * 129 * 512 + i * 512 + j * 64 + nt * 16 + c] : 0.f;
    __hip_bfloat16 hi = __float2bfloat16(wv);
    Whi[idx] = hi;
    Wlo[idx] = __float2bfloat16(wv - __bfloat162float(hi));
}

__device__ __forceinline__ void wm1z_body(
        int idx, const float* __restrict__ Wm1, __hip_bfloat16* __restrict__ Whi) {
    int l = idx / 71680;
    int rem = idx % 71680;
    int kkn = rem >> 9;          // 0..139
    int off = rem & 511;
    int kk = kkn >> 2;
    int nt = kkn & 3;
    int q   = (off >> 7) & 3;
    int c16 = (off >> 3) & 15;
    int j = off & 7;
    int k = nt * 16 + c16;
    int wi = -1;
    if (kk < 17) { int i = q * 17 + kk; if (i <= 64) wi = i; }
    else if (kk < 34) { int s = q * 17 + (kk - 17); if (s <= 64) wi = 65 + s; }
    else { if (q == 0) wi = 130; }
    float wv = (wi >= 0) ? Wm1[((size_t)l * 131 + wi) * 512 + j * 64 + k] : 0.f;
    Whi[idx] = __float2bfloat16(wv);
}

// ---------------- mega pre-kernel: all weight reorders + hist zero + embed ----------------
constexpr int PB_W2H  = 0;                 // 256 blocks: Wm2 -> W2hi
constexpr int PB_WM1Z = PB_W2H  + 256;     // 560
constexpr int PB_WU1  = PB_WM1Z + 560;     // 528
constexpr int PB_WU2  = PB_WU1  + 528;     // 256
constexpr int PB_WP1  = PB_WU2  + 256;     // 128
constexpr int PB_WP2  = PB_WP1  + 128;     // 128
constexpr int PB_ZERO = PB_WP2  + 128;     // 40
constexpr int PB_EMB  = PB_ZERO + 40;      // 625
constexpr int PB_TOTAL= PB_EMB  + 625;     // 2521

__global__ __launch_bounds__(256) void k_pre(
        const float* __restrict__ Wm2, __hip_bfloat16* __restrict__ W2hi,
        const float* __restrict__ Wm1, __hip_bfloat16* __restrict__ Wm1zhi,
        const float* __restrict__ Wu1w, __hip_bfloat16* __restrict__ Wu1hi, __hip_bfloat16* __restrict__ Wu1lo,
        const float* __restrict__ Wu2w, __hip_bfloat16* __restrict__ Wu2hi, __hip_bfloat16* __restrict__ Wu2lo,
        const float* __restrict__ Wp1w, __hip_bfloat16* __restrict__ Wp1hi, __hip_bfloat16* __restrict__ Wp1lo,
        const float* __restrict__ Wp2w, __hip_bfloat16* __restrict__ Wp2hi, __hip_bfloat16* __restrict__ Wp2lo,
        int* __restrict__ hist,
        const float* __restrict__ x, const float* __restrict__ anf,
        const float* __restrict__ na, const float* __restrict__ W_emb,
        const float* __restrict__ b_emb,
        float* __restrict__ h, __hip_bfloat16* __restrict__ hb, float* __restrict__ agg) {
    __shared__ float xs[16][18];
    __shared__ float na_s[16][8];
    int tid = threadIdx.x;
    int bx = blockIdx.x;
    if (bx < PB_WM1Z) {
        w2h_body((bx - PB_W2H) * 256 + tid, Wm2, W2hi);
    } else if (bx < PB_WU1) {
        wm1z_body((bx - PB_WM1Z) * 256 + tid, Wm1, Wm1zhi);
    } else if (bx < PB_WU2) {
        wu1_body((bx - PB_WU1) * 256 + tid, Wu1w, Wu1hi, Wu1lo);
    } else if (bx < PB_WP1) {
        w2_body((bx - PB_WU2) * 256 + tid, Wu2w, Wu2hi, Wu2lo);
    } else if (bx < PB_WP2) {
        w2_body((bx - PB_WP1) * 256 + tid, Wp1w, Wp1hi, Wp1lo);
    } else if (bx < PB_ZERO) {
        w2_body((bx - PB_WP2) * 256 + tid, Wp2w, Wp2hi, Wp2lo);
    } else if (bx < PB_EMB) {
        int i = (bx - PB_ZERO) * 256 + tid;
        if (i < N) hist[i] = 0;
    } else {
        // ---- embed: h fp32 + hb (q-sectioned) + agg zero ----
        int eb = bx - PB_EMB;
        int w = tid >> 6, l = tid & 63;
        int n0 = eb * 16;
        {
            int r = tid >> 4, c = tid & 15;
            xs[r][c] = x[(size_t)(n0 + r) * 16 + c];
        }
        if (tid < 16) xs[tid][16] = anf[n0 + tid];
        if (tid < 128) na_s[tid >> 3][tid & 7] = na[(size_t)n0 * 8 + tid];
        float4 z4 = {0.f, 0.f, 0.f, 0.f};
        ((float4*)(agg + (size_t)eb * 1024))[tid] = z4;
        for (int t = tid; t < 192; t += 256)
            ((float4*)(hb + (size_t)n0 * HS))[t] = z4;
        __syncthreads();
        float acc[4];
#pragma unroll
        for (int t = 0; t < 4; ++t) acc[t] = b_emb[l];
        for (int i = 0; i < 17; ++i) {
#pragma unroll
            for (int j = 0; j < 8; ++j) {
                float wv = W_emb[(i * 8 + j) * 64 + l];
#pragma unroll
                for (int t = 0; t < 4; ++t) {
                    int nn = w * 4 + t;
                    acc[t] = fmaf(xs[nn][i] * na_s[nn][j], wv, acc[t]);
                }
            }
        }
        int slot = (l / 17) * 24 + l % 17;
#pragma unroll
        for (int t = 0; t < 4; ++t) {
            int n = n0 + w * 4 + t;
            h[(size_t)n * 64 + l] = acc[t];
            hb[(size_t)n * HS + slot] = __float2bfloat16(acc[t]);
        }
        if (tid < 16) hb[(size_t)(n0 + tid) * HS + 85] = __float2bfloat16(xs[tid][16]);
    }
}

// ---------------- edge sort by dst: histogram / scan / scatter+materialize ----------------
__global__ __launch_bounds__(256) void k_hist(
        const int* __restrict__ eidx, int* __restrict__ hist) {
    int e = blockIdx.x * 256 + threadIdx.x;
    if (e < E) atomicAdd(&hist[eidx[E + e]], 1);
}

// single-block exclusive scan over N=10000 bins -> cursor
__global__ __launch_bounds__(1024) void k_scan(
        const int* __restrict__ hist, int* __restrict__ cursor) {
    __shared__ int wsum[16];
    int t = threadIdx.x;
    int base = t * 10;
    int loc[10];
    int s = 0;
#pragma unroll
    for (int i = 0; i < 10; ++i) {
        int v = (base + i < N) ? hist[base + i] : 0;
        loc[i] = s;
        s += v;
    }
    int lane = t & 63, w = t >> 6;
    int incl = s;
    for (int off = 1; off < 64; off <<= 1) {
        int u = __shfl_up(incl, off, 64);
        if (lane >= off) incl += u;
    }
    if (lane == 63) wsum[w] = incl;
    __syncthreads();
    if (t == 0) {
        int a = 0;
        for (int i2 = 0; i2 < 16; ++i2) { int v = wsum[i2]; wsum[i2] = a; a += v; }
    }
    __syncthreads();
    int excl = incl - s + wsum[w];
#pragma unroll
    for (int i = 0; i < 10; ++i) {
        int p = base + i;
        if (p < N) cursor[p] = excl + loc[i];
    }
}

// scatter into dst-sorted records (coalesced reads; 48B record = 1-2 line touches/edge)
__global__ __launch_bounds__(256) void k_scatter_sort(
        const int* __restrict__ eidx, const float* __restrict__ ea,
        const float* __restrict__ amf, int* __restrict__ cursor,
        int* __restrict__ dstS, float4* __restrict__ recs) {
    int e = blockIdx.x * 256 + threadIdx.x;
    if (e < E) {
        int d = eidx[E + e];
        int p = atomicAdd(&cursor[d], 1);
        dstS[p] = d;
        float4 a0 = ((const float4*)ea)[(size_t)e * 2];
        float4 a1 = ((const float4*)ea)[(size_t)e * 2 + 1];
        float4 r0 = {__int_as_float(eidx[e]), amf[e], a0.x, a0.y};
        float4 r1 = {a0.z, a0.w, a1.x, a1.y};
        float4 r2 = {a1.z, a1.w, 0.f, 0.f};
        recs[(size_t)p * 3 + 0] = r0;
        recs[(size_t)p * 3 + 1] = r1;
        recs[(size_t)p * 3 + 2] = r2;
    }
}

// ---------------- K3: edge kernel — LDS-staged weights via async DMA (r9/r10 base, 256 thr) ----------------
// ONLY change vs the passing r10 kernel: lofs = l*8 (conflict-free slot layout).
__global__ __launch_bounds__(256, 3) void k_edge(
        const float4* __restrict__ recs, const int* __restrict__ dstS,
        const __hip_bfloat16* __restrict__ hb,
        const __hip_bfloat16* __restrict__ W1hi, const float* __restrict__ bm1_l,
        const __hip_bfloat16* __restrict__ W2hi,
        const float* __restrict__ bm2_l, float* __restrict__ agg) {
    __shared__ __align__(16) __hip_bfloat16 wbuf[2][8192];   // 2 x 16KB weight chunks
    // per-wave private 4608B region: m_s [32][72] bf16; m2 chunk [16][66] f32 overlaid
    __shared__ __align__(16) char smem_u[4 * 4608];          // 18432 B
    __shared__ int dst_s[128];
    int tid = threadIdx.x;
    int l = tid & 63, w = tid >> 6;
    int e0 = blockIdx.x * 128;
    __hip_bfloat16* m_s = (__hip_bfloat16*)(smem_u + w * 4608);
    float* m2 = (float*)(smem_u + w * 4608);

    if (l < 32) dst_s[w * 32 + l] = dstS[e0 + w * 32 + l];

    int c16 = l & 15, q = l >> 4;
    int e0w = w * 32;
    float eaA[2][8], amfA[2];
    int dL[2], sL[2];
#pragma unroll
    for (int mt = 0; mt < 2; ++mt) {
        int e = e0 + e0w + mt * 16 + c16;
        float4 r0 = recs[(size_t)e * 3];
        float4 r1 = recs[(size_t)e * 3 + 1];
        float4 r2 = recs[(size_t)e * 3 + 2];
        sL[mt] = __float_as_int(r0.x);
        amfA[mt] = r0.y;
        eaA[mt][0] = r0.z; eaA[mt][1] = r0.w;
        eaA[mt][2] = r1.x; eaA[mt][3] = r1.y; eaA[mt][4] = r1.z; eaA[mt][5] = r1.w;
        eaA[mt][6] = r2.x; eaA[mt][7] = r2.y;
        dL[mt] = dstS[e];
    }
    float bR1[4], bR2[4];
#pragma unroll
    for (int nt = 0; nt < 4; ++nt) {
        bR1[nt] = bm1_l[nt * 16 + c16];
        bR2[nt] = bm2_l[nt * 16 + c16];
    }
    int lofs = l * 8;                                        // conflict-free slot layout
    f32x4 zero4 = {0.f, 0.f, 0.f, 0.f};

    // async-DMA staging of one 16KB chunk (nk*4KB): per round r, wave w covers 1KB.
    auto stage = [&](const __hip_bfloat16* src, __hip_bfloat16* dbuf, int nk) {
        const char* g = (const char*)src;
        char* lb = (char*)dbuf;
#pragma unroll
        for (int r = 0; r < 4; ++r)
            if (r < nk)
                gload_lds16(g + (size_t)(r * 256 + w * 64 + l) * 16,
                            lb + (r * 256 + w * 64) * 16);
    };

    // gather D-side fragments only (S-side deferred to c==3)
    bf16x4 xD[2][5];
#pragma unroll
    for (int mt = 0; mt < 2; ++mt) {
        const __hip_bfloat16* bd = hb + (size_t)dL[mt] * HS + q * 24;
#pragma unroll
        for (int t = 0; t < 5; ++t)
            xD[mt][t] = *(const bf16x4*)(bd + t * 4);
    }

    // issue chunk 0 DMA (drained by the first in-loop barrier)
    stage(W1hi, wbuf[0], 4);

    f32x4 acc[2][4];
#pragma unroll
    for (int mt = 0; mt < 2; ++mt)
#pragma unroll
        for (int nt = 0; nt < 4; ++nt) acc[mt][nt] = zero4;
    bf16x4 xS[2][5];    // loaded at c==3
    bf16x4 mR[2][4];    // loaded at c==8

    // 13 chunks: c 0..8 = W1 (8x4kk + 1x3kk), c 9..12 = W2 (4x4kk)
#pragma unroll
    for (int c = 0; c < 13; ++c) {
        __syncthreads();   // drains each wave's own DMA (vmcnt(0)) then syncs -> buf[c&1] ready
        if (c + 1 < 13) {
            const __hip_bfloat16* nsrc = (c + 1 < 9) ? (W1hi + (c + 1) * 8192)
                                                     : (W2hi + (c + 1 - 9) * 8192);
            stage(nsrc, wbuf[(c + 1) & 1], (c + 1 == 8) ? 3 : 4);
        }
        if (c == 3) {
#pragma unroll
            for (int mt = 0; mt < 2; ++mt) {
                const __hip_bfloat16* bs = hb + (size_t)sL[mt] * HS + q * 24;
#pragma unroll
                for (int t = 0; t < 5; ++t)
                    xS[mt][t] = *(const bf16x4*)(bs + t * 4);
            }
        }
        const __hip_bfloat16* wb = wbuf[c & 1];
        if (c < 9) {
            const int nkk = (c == 8) ? 3 : 4;
#pragma unroll
            for (int kkl = 0; kkl < 4; ++kkl) {
                if (kkl < nkk) {
                    const int u = c * 4 + kkl;      // 0..34
                    bf16x8 bh[4];
#pragma unroll
                    for (int nt = 0; nt < 4; ++nt)
                        bh[nt] = *(const bf16x8*)&wb[(kkl * 4 + nt) * 512 + lofs];
#pragma unroll
                    for (int mt = 0; mt < 2; ++mt) {
                        float xv;
                        if (u < 17)      xv = bf2f(xD[mt][u >> 2][u & 3]);
                        else if (u < 34) { const int s = u - 17; xv = bf2f(xS[mt][s >> 2][s & 3]); }
                        else             xv = (q == 0) ? amfA[mt] : 0.f;
                        union { bf16x8 v; __hip_bfloat16 hx[8]; } au;
#pragma unroll
                        for (int j = 0; j < 8; ++j) au.hx[j] = __float2bfloat16(xv * eaA[mt][j]);
#pragma unroll
                        for (int nt = 0; nt < 4; ++nt)
                            acc[mt][nt] = __builtin_amdgcn_mfma_f32_16x16x32_bf16(au.v, bh[nt], acc[mt][nt], 0, 0, 0);
                    }
                }
            }
        } else {
#pragma unroll
            for (int kkl = 0; kkl < 4; ++kkl) {
                const int kk = (c - 9) * 4 + kkl;   // 0..15
                bf16x8 bh[4];
#pragma unroll
                for (int nt = 0; nt < 4; ++nt)
                    bh[nt] = *(const bf16x8*)&wb[(kkl * 4 + nt) * 512 + lofs];
#pragma unroll
                for (int mt = 0; mt < 2; ++mt) {
                    float mv = bf2f(mR[mt][kk >> 2][kk & 3]);
                    union { bf16x8 v; __hip_bfloat16 hx[8]; } au;
#pragma unroll
                    for (int j = 0; j < 8; ++j) au.hx[j] = __float2bfloat16(mv * eaA[mt][j]);
#pragma unroll
                    for (int nt = 0; nt < 4; ++nt)
                        acc[mt][nt] = __builtin_amdgcn_mfma_f32_16x16x32_bf16(au.v, bh[nt], acc[mt][nt], 0, 0, 0);
                }
            }
        }
        if (c == 8) {
#pragma unroll
            for (int mt = 0; mt < 2; ++mt)
#pragma unroll
                for (int nt = 0; nt < 4; ++nt) {
                    int kd = nt * 16 + c16;
                    float bias = bR1[nt];
#pragma unroll
                    for (int r = 0; r < 4; ++r) {
                        int el = mt * 16 + q * 4 + r;
                        m_s[el * MS + kd] = __float2bfloat16(silu_f(bias + acc[mt][nt][r]));
                    }
                }
#pragma unroll
            for (int mt = 0; mt < 2; ++mt)
#pragma unroll
                for (int t = 0; t < 4; ++t)
                    mR[mt][t] = *(const bf16x4*)&m_s[(mt * 16 + c16) * MS + q * 16 + t * 4];
            asm volatile("" ::: "memory");
#pragma unroll
            for (int mt = 0; mt < 2; ++mt)
#pragma unroll
                for (int nt = 0; nt < 4; ++nt) acc[mt][nt] = zero4;   // reuse for phase 2
        }
    }

    // chunked epilogue: per mt-chunk write 16 rows of m2 (own region), run-length reduce, atomics.
#pragma unroll
    for (int mt = 0; mt < 2; ++mt) {
#pragma unroll
        for (int nt = 0; nt < 4; ++nt) {
            int kd = nt * 16 + c16;
            float bias = bR2[nt];
#pragma unroll
            for (int r = 0; r < 4; ++r)
                m2[(q * 4 + r) * 66 + kd] = silu_f(bias + acc[mt][nt][r]);
        }
        int rb = w * 32 + mt * 16;
        float run = 0.f;
        int cur_d = dst_s[rb];
        for (int i = 0; i < 16; ++i) {
            int d = dst_s[rb + i];                 // wave-uniform
            if (d != cur_d) {
                atomicAdd(&agg[(size_t)cur_d * 64 + l], run);
                run = 0.f;
                cur_d = d;
            }
            run += m2[i * 66 + l];
        }
        atomicAdd(&agg[(size_t)cur_d * 64 + l], run);
        asm volatile("" ::: "memory");
    }
}

// ---------------- K4: node update — nt-split waves + async-DMA weight staging ----------------
__global__ __launch_bounds__(256) void k_upd_hb(
        const float* __restrict__ h_in, const float* __restrict__ anf,
        const float* __restrict__ na, const float* __restrict__ agg_in,
        const __hip_bfloat16* __restrict__ W1hi, const __hip_bfloat16* __restrict__ W1lo,
        const float* __restrict__ bu1_l,
        const __hip_bfloat16* __restrict__ W2hi_, const __hip_bfloat16* __restrict__ W2lo_,
        const float* __restrict__ bu2_l,
        float* __restrict__ h, __hip_bfloat16* __restrict__ hb, float* __restrict__ agg) {
    __shared__ __align__(16) __hip_bfloat16 wbuf[2][8192];   // [0..4096) hi, [4096..8192) lo
    __shared__ __align__(16) __hip_bfloat16 xa_s[16 * 136];
    __shared__ __align__(16) __hip_bfloat16 u1_s[16 * 72];
    int tid = threadIdx.x;
    int w = tid >> 6, l = tid & 63;
    int n0 = blockIdx.x * 16;
    for (int idx = tid; idx < 16 * 132; idx += 256) {
        int r = idx / 132, c = idx % 132;
        int n = n0 + r;
        float v;
        if (c < 64) v = h_in[(size_t)n * 64 + c];
        else if (c == 64) v = anf[n];
        else if (c < 129) v = agg_in[(size_t)n * 64 + (c - 65)];
        else v = 0.f;
        xa_s[r * 136 + c] = __float2bfloat16(v);
    }
    int c16 = l & 15, q = l >> 4;
    float naA[8];
#pragma unroll
    for (int j = 0; j < 8; ++j) naA[j] = na[(size_t)(n0 + c16) * 8 + j];
    int col = w * 16 + c16;
    float bu1R = bu1_l[col], bu2R = bu2_l[col];
    float4 z4 = {0.f, 0.f, 0.f, 0.f};
    ((float4*)(agg + (size_t)blockIdx.x * 1024))[tid] = z4;
    for (int t = tid; t < 192; t += 256)
        ((float4*)(hb + (size_t)n0 * HS))[t] = z4;
    int lofs = l * 8;                                        // conflict-free slot layout

    auto stage_ul = [&](const __hip_bfloat16* hi, const __hip_bfloat16* lo,
                        __hip_bfloat16* buf, int nr) {
        const char* gh = (const char*)hi;
        const char* gl = (const char*)lo;
        char* bh = (char*)buf;
        char* bl = (char*)(buf + 4096);
#pragma unroll
        for (int r = 0; r < 2; ++r)
            if (r < nr) {
                gload_lds16(gh + (size_t)(r * 256 + w * 64 + l) * 16, bh + (r * 256 + w * 64) * 16);
                gload_lds16(gl + (size_t)(r * 256 + w * 64 + l) * 16, bl + (r * 256 + w * 64) * 16);
            }
    };

    stage_ul(W1hi, W1lo, wbuf[0], 2);
    f32x4 zero4 = {0.f, 0.f, 0.f, 0.f};
    f32x4 acc = zero4;
#pragma unroll 1
    for (int c = 0; c < 25; ++c) {
        __syncthreads();            // drains own DMA + publishes buf[c&1] + orders u1_s
        if (c + 1 < 25) {
            int cn = c + 1;
            const __hip_bfloat16 *nh, *nl;
            int nr = 2;
            if (cn < 17) { nh = W1hi + cn * 4096; nl = W1lo + cn * 4096; if (cn == 16) nr = 1; }
            else         { nh = W2hi_ + (cn - 17) * 4096; nl = W2lo_ + (cn - 17) * 4096; }
            stage_ul(nh, nl, wbuf[cn & 1], nr);
        }
        const __hip_bfloat16* wb = wbuf[c & 1];
        const __hip_bfloat16* xs;
        int xstr, Lq, kk0, nkl = 2;
        if (c < 17) { xs = xa_s; xstr = 136; Lq = 33; kk0 = c * 2; if (c == 16) nkl = 1; }
        else        { xs = u1_s; xstr = 72;  Lq = 16; kk0 = (c - 17) * 2; }
#pragma unroll
        for (int kl = 0; kl < 2; ++kl)
            if (kl < nkl) {
                float mv = __bfloat162float(xs[c16 * xstr + q * Lq + kk0 + kl]);
                union { bf16x8 v; __hip_bfloat16 hx[8]; } au;
#pragma unroll
                for (int j = 0; j < 8; ++j) au.hx[j] = __float2bfloat16(mv * naA[j]);
                bf16x8 bh = *(const bf16x8*)&wb[(kl * 4 + w) * 512 + lofs];
                bf16x8 bl = *(const bf16x8*)&wb[4096 + (kl * 4 + w) * 512 + lofs];
                acc = __builtin_amdgcn_mfma_f32_16x16x32_bf16(au.v, bh, acc, 0, 0, 0);
                acc = __builtin_amdgcn_mfma_f32_16x16x32_bf16(au.v, bl, acc, 0, 0, 0);
            }
        if (c == 16) {
#pragma unroll
            for (int r = 0; r < 4; ++r)
                u1_s[(q * 4 + r) * 72 + col] = __float2bfloat16(silu_f(acc[r] + bu1R));
            acc = zero4;
        }
    }
    int slot = (col / 17) * 24 + col % 17;
#pragma unroll
    for (int r = 0; r < 4; ++r) {
        int n = n0 + q * 4 + r;
        float hn = h[(size_t)n * 64 + col] + acc[r] + bu2R;
        h[(size_t)n * 64 + col] = hn;
        hb[(size_t)n * HS + slot] = __float2bfloat16(hn);
    }
    if (tid < 16) hb[(size_t)(n0 + tid) * HS + 85] = __float2bfloat16(anf[n0 + tid]);
}

// ---------------- K6: fused node update (layer 1) + prepool — same template, 41 chunks ----------------
__global__ __launch_bounds__(256) void k_upd_prepool(
        const float* __restrict__ h_in, const float* __restrict__ anf,
        const float* __restrict__ na, const float* __restrict__ agg_in,
        const __hip_bfloat16* __restrict__ W1hi, const __hip_bfloat16* __restrict__ W1lo,
        const float* __restrict__ bu1_l,
        const __hip_bfloat16* __restrict__ W2hi_, const __hip_bfloat16* __restrict__ W2lo_,
        const float* __restrict__ bu2_l,
        const __hip_bfloat16* __restrict__ Wp1hi, const __hip_bfloat16* __restrict__ Wp1lo,
        const float* __restrict__ bp1,
        const __hip_bfloat16* __restrict__ Wp2hi, const __hip_bfloat16* __restrict__ Wp2lo,
        const float* __restrict__ bp2,
        float* __restrict__ p2) {
    __shared__ __align__(16) __hip_bfloat16 wbuf[2][8192];
    __shared__ __align__(16) __hip_bfloat16 xa_s[16 * 136];
    __shared__ __align__(16) __hip_bfloat16 u1_s[16 * 72];
    __shared__ __align__(16) __hip_bfloat16 x2_s[16 * 72];
    int tid = threadIdx.x;
    int w = tid >> 6, l = tid & 63;
    int n0 = blockIdx.x * 16;
    for (int idx = tid; idx < 16 * 132; idx += 256) {
        int r = idx / 132, c = idx % 132;
        int n = n0 + r;
        float v;
        if (c < 64) v = h_in[(size_t)n * 64 + c];
        else if (c == 64) v = anf[n];
        else if (c < 129) v = agg_in[(size_t)n * 64 + (c - 65)];
        else v = 0.f;
        xa_s[r * 136 + c] = __float2bfloat16(v);
    }
    int c16 = l & 15, q = l >> 4;
    float naA[8];
#pragma unroll
    for (int j = 0; j < 8; ++j) naA[j] = na[(size_t)(n0 + c16) * 8 + j];
    int col = w * 16 + c16;
    float bu1R = bu1_l[col], bu2R = bu2_l[col];
    float bp1R = bp1[col], bp2R = bp2[col];
    int lofs = l * 8;                                        // conflict-free slot layout

    auto stage_ul = [&](const __hip_bfloat16* hi, const __hip_bfloat16* lo,
                        __hip_bfloat16* buf, int nr) {
        const char* gh = (const char*)hi;
        const char* gl = (const char*)lo;
        char* bh = (char*)buf;
        char* bl = (char*)(buf + 4096);
#pragma unroll
        for (int r = 0; r < 2; ++r)
            if (r < nr) {
                gload_lds16(gh + (size_t)(r * 256 + w * 64 + l) * 16, bh + (r * 256 + w * 64) * 16);
                gload_lds16(gl + (size_t)(r * 256 + w * 64 + l) * 16, bl + (r * 256 + w * 64) * 16);
            }
    };

    stage_ul(W1hi, W1lo, wbuf[0], 2);
    f32x4 zero4 = {0.f, 0.f, 0.f, 0.f};
    f32x4 acc = zero4;
#pragma unroll 1
    for (int c = 0; c < 41; ++c) {
        __syncthreads();
        if (c + 1 < 41) {
            int cn = c + 1;
            const __hip_bfloat16 *nh, *nl;
            int nr = 2;
            if (cn < 17)      { nh = W1hi + cn * 4096;        nl = W1lo + cn * 4096;        if (cn == 16) nr = 1; }
            else if (cn < 25) { nh = W2hi_ + (cn - 17) * 4096; nl = W2lo_ + (cn - 17) * 4096; }
            else if (cn < 33) { nh = Wp1hi + (cn - 25) * 4096; nl = Wp1lo + (cn - 25) * 4096; }
            else              { nh = Wp2hi + (cn - 33) * 4096; nl = Wp2lo + (cn - 33) * 4096; }
            stage_ul(nh, nl, wbuf[cn & 1], nr);
        }
        const __hip_bfloat16* wb = wbuf[c & 1];
        const __hip_bfloat16* xs;
        int xstr, Lq, kk0, nkl = 2;
        if (c < 17)      { xs = xa_s; xstr = 136; Lq = 33; kk0 = c * 2; if (c == 16) nkl = 1; }
        else if (c < 25) { xs = u1_s; xstr = 72;  Lq = 16; kk0 = (c - 17) * 2; }
        else if (c < 33) { xs = x2_s; xstr = 72;  Lq = 16; kk0 = (c - 25) * 2; }
        else             { xs = u1_s; xstr = 72;  Lq = 16; kk0 = (c - 33) * 2; }
#pragma unroll
        for (int kl = 0; kl < 2; ++kl)
            if (kl < nkl) {
                float mv = __bfloat162float(xs[c16 * xstr + q * Lq + kk0 + kl]);
                union { bf16x8 v; __hip_bfloat16 hx[8]; } au;
#pragma unroll
                for (int j = 0; j < 8; ++j) au.hx[j] = __float2bfloat16(mv * naA[j]);
                bf16x8 bh = *(const bf16x8*)&wb[(kl * 4 + w) * 512 + lofs];
                bf16x8 bl = *(const bf16x8*)&wb[4096 + (kl * 4 + w) * 512 + lofs];
                acc = __builtin_amdgcn_mfma_f32_16x16x32_bf16(au.v, bh, acc, 0, 0, 0);
                acc = __builtin_amdgcn_mfma_f32_16x16x32_bf16(au.v, bl, acc, 0, 0, 0);
            }
        if (c == 16) {
#pragma unroll
            for (int r = 0; r < 4; ++r)
                u1_s[(q * 4 + r) * 72 + col] = __float2bfloat16(silu_f(acc[r] + bu1R));
            acc = zero4;
        } else if (c == 24) {
#pragma unroll
            for (int r = 0; r < 4; ++r) {
                int n = n0 + q * 4 + r;
                float hn = h_in[(size_t)n * 64 + col] + acc[r] + bu2R;
                x2_s[(q * 4 + r) * 72 + col] = __float2bfloat16(hn);
            }
            acc = zero4;
        } else if (c == 32) {
#pragma unroll
            for (int r = 0; r < 4; ++r)
                u1_s[(q * 4 + r) * 72 + col] = __float2bfloat16(silu_f(acc[r] + bp1R));
            acc = zero4;
        }
    }
#pragma unroll
    for (int r = 0; r < 4; ++r)
        p2[(size_t)(n0 + q * 4 + r) * 64 + col] = acc[r] + bp2R;
}

// ---------------- K_pool ----------------
__global__ __launch_bounds__(256) void k_pool(
        const float* __restrict__ p2, const int* __restrict__ batch,
        float* __restrict__ partial_p, float* __restrict__ partial_cnt) {
    __shared__ float acc_s[16 * 64];
    __shared__ float cnt_s[16];
    int tid = threadIdx.x;
    for (int idx = tid; idx < 1024; idx += 256) acc_s[idx] = 0.f;
    if (tid < 16) cnt_s[tid] = 0.f;
    __syncthreads();
    int w = tid >> 6, k = tid & 63;
    int base = blockIdx.x * 125;
    for (int i = 0; i < 32; ++i) {
        int nl = i * 4 + w;
        if (nl < 125) {
            int n = base + nl;
            int b = batch[n];
            atomicAdd(&acc_s[b * 64 + k], p2[(size_t)n * 64 + k]);
            if (k == 0) atomicAdd(&cnt_s[b], 1.0f);
        }
    }
    __syncthreads();
    for (int idx = tid; idx < 1024; idx += 256)
        partial_p[(size_t)blockIdx.x * 1024 + idx] = acc_s[idx];
    if (tid < 16) partial_cnt[blockIdx.x * 16 + tid] = cnt_s[tid];
}

// ---------------- K7: reduce partials, mean, final MLP ----------------
__global__ __launch_bounds__(1024) void k_final(
        const float* __restrict__ partial_p, const float* __restrict__ partial_cnt,
        const float* __restrict__ Wq1, const float* __restrict__ bq1,
        const float* __restrict__ Wq2, const float* __restrict__ bq2,
        float* __restrict__ out) {
    __shared__ float g[16][64];
    int b = threadIdx.x >> 6, k = threadIdx.x & 63;
    float s = 0.f, cc = 0.f;
    for (int c = 0; c < POOL_CHUNKS; ++c) s += partial_p[(size_t)c * 1024 + b * 64 + k];
    for (int c = 0; c < POOL_CHUNKS; ++c) cc += partial_cnt[c * 16 + b];
    g[b][k] = s / fmaxf(cc, 1.0f);
    __syncthreads();
    float acc = bq1[k];
#pragma unroll
    for (int i = 0; i < 64; ++i) acc = fmaf(g[b][i], Wq1[i * 64 + k], acc);
    float v = silu_f(acc) * Wq2[k];
#pragma unroll
    for (int off = 32; off > 0; off >>= 1) v += __shfl_down(v, off, 64);
    if (k == 0) out[b] = v + bq2[0];
}

extern "C" void kernel_launch(void* const* d_in, const int* in_sizes, int n_in,
                              void* d_out, int out_size, void* d_ws, size_t ws_size,
                              hipStream_t stream) {
    const float* x    = (const float*)d_in[0];
    const int*   eidx = (const int*)  d_in[1];
    const float* ea   = (const float*)d_in[2];
    const float* na   = (const float*)d_in[3];
    const float* amf  = (const float*)d_in[4];
    const float* anf  = (const float*)d_in[5];
    const int*   batch= (const int*)  d_in[6];
    const float* W_emb= (const float*)d_in[7];
    const float* b_emb= (const float*)d_in[8];
    const float* Wm1  = (const float*)d_in[9];
    const float* bm1  = (const float*)d_in[10];
    const float* Wm2  = (const float*)d_in[11];
    const float* bm2  = (const float*)d_in[12];
    const float* Wu1  = (const float*)d_in[13];
    const float* bu1  = (const float*)d_in[14];
    const float* Wu2  = (const float*)d_in[15];
    const float* bu2  = (const float*)d_in[16];
    const float* Wp1  = (const float*)d_in[17];
    const float* bp1  = (const float*)d_in[18];
    const float* Wp2  = (const float*)d_in[19];
    const float* bp2  = (const float*)d_in[20];
    const float* Wq1  = (const float*)d_in[21];
    const float* bq1  = (const float*)d_in[22];
    const float* Wq2  = (const float*)d_in[23];
    const float* bq2  = (const float*)d_in[24];

    float* ws = (float*)d_ws;
    float* h      = ws;                            // N*64
    float* agg    = h + (size_t)N * 64;            // N*64
    float* p2     = agg + (size_t)N * 64;          // N*64
    float* part_p = p2 + (size_t)N * 64;           // 80*1024
    float* part_c = part_p + POOL_CHUNKS * 1024;   // 80*16
    float* fend   = part_c + POOL_CHUNKS * 16;
    __hip_bfloat16* hb     = (__hip_bfloat16*)fend;          // N*96
    __hip_bfloat16* W2hi   = hb + (size_t)N * HS;            // 2*32768
    __hip_bfloat16* Wm1zhi = W2hi + 65536;                   // 2*71680
    __hip_bfloat16* Wu1hi  = Wm1zhi + 143360;                // 2*67584
    __hip_bfloat16* Wu1lo  = Wu1hi + 135168;
    __hip_bfloat16* Wu2hi  = Wu1lo + 135168;                 // 2*32768
    __hip_bfloat16* Wu2lo  = Wu2hi + 65536;
    __hip_bfloat16* Wp1hi  = Wu2lo + 65536;                  // 32768
    __hip_bfloat16* Wp1lo  = Wp1hi + 32768;
    __hip_bfloat16* Wp2hi  = Wp1lo + 32768;
    __hip_bfloat16* Wp2lo  = Wp2hi + 32768;
    int* hist   = (int*)(Wp2lo + 32768);                     // N
    int* cursor = hist + N;                                  // N
    int* dstS   = cursor + N;                                // E
    float4* recs = (float4*)(dstS + E);                      // E * 3 float4 (48B/edge)

    // mega pre-kernel: all weight reorders + hist zero + embed(+agg/hb init)
    k_pre<<<PB_TOTAL, 256, 0, stream>>>(
        Wm2, W2hi, Wm1, Wm1zhi, Wu1, Wu1hi, Wu1lo, Wu2, Wu2hi, Wu2lo,
        Wp1, Wp1hi, Wp1lo, Wp2, Wp2hi, Wp2lo, hist,
        x, anf, na, W_emb, b_emb, h, hb, agg);

    // dst-sort + materialize sorted edge records (reused by both edge dispatches)
    k_hist<<<(E + 255) / 256, 256, 0, stream>>>(eidx, hist);
    k_scan<<<1, 1024, 0, stream>>>(hist, cursor);
    k_scatter_sort<<<(E + 255) / 256, 256, 0, stream>>>(eidx, ea, amf, cursor, dstS, recs);

    k_edge<<<E / 128, 256, 0, stream>>>(recs, dstS, hb,
                                        Wm1zhi, bm1, W2hi, bm2, agg);
    k_upd_hb<<<625, 256, 0, stream>>>(h, anf, na, agg,
                                      Wu1hi, Wu1lo, bu1,
                                      Wu2hi, Wu2lo, bu2,
                                      h, hb, agg);
    k_edge<<<E / 128, 256, 0, stream>>>(recs, dstS, hb,
                                        Wm1zhi + 71680, bm1 + 64,
                                        W2hi + 32768, bm2 + 64, agg);
    k_upd_prepool<<<625, 256, 0, stream>>>(h, anf, na, agg,
                                           Wu1hi + 67584, Wu1lo + 67584, bu1 + 64,
                                           Wu2hi + 32768, Wu2lo + 32768, bu2 + 64,
                                           Wp1hi, Wp1lo, bp1, Wp2hi, Wp2lo, bp2, p2);
    k_pool<<<POOL_CHUNKS, 256, 0, stream>>>(p2, batch, part_p, part_c);
    k_final<<<1, 1024, 0, stream>>>(part_p, part_c, Wq1, bq1, Wq2, bq2, (float*)d_out);
}